// Round 10
// baseline (794.636 us; speedup 1.0000x reference)
//
#include <hip/hip_runtime.h>
#include <cstdint>
#include <cstddef>

// ---------------------------------------------------------------------------
// DeeperGCN forward on MI355X. Round 10: latency-chain surgery on the fused
// layer kernel. (a) Block's CSR edge-index segment staged into LDS (one
// global-latency level per gather instead of two), (b) gemm1 weight frags
// prefetched into registers before agg (L2 latency overlaps gather phase),
// (c) h residual prefetched at kernel start. 16-row tiles, 625 blocks,
// max-free softmax agg with 2 nodes x 4 chains per wave.
// N=10000 nodes, E=160000 edges, H=128, L=14 layers, G=64 graphs.
// ---------------------------------------------------------------------------

#define BT 512   // 8 waves
#define ECAP 1024  // LDS edge-index cache entries per block

typedef __attribute__((ext_vector_type(8))) short bf16x8;
typedef __attribute__((ext_vector_type(4))) float f32x4;

__device__ inline float bf2f(ushort u) {
    union { uint i; float f; } v;
    v.i = (uint)u << 16;
    return v.f;
}
__device__ inline ushort f2bf(float f) {
    union { float f; uint i; } v;
    v.f = f;
    return (ushort)((v.i + 0x7fffu + ((v.i >> 16) & 1u)) >> 16);
}
__device__ inline uint f2bf2(float a, float b) {
    return (uint)f2bf(a) | ((uint)f2bf(b) << 16);
}

__device__ inline float wave_sum_f(float v) {
#pragma unroll
    for (int off = 32; off > 0; off >>= 1) v += __shfl_xor(v, off, 64);
    return v;
}

// ---------------- setup: xb convert + deg histogram + graph boundaries -----
__global__ void setup_kernel(const float* __restrict__ x, ushort* __restrict__ xb,
                             const int* __restrict__ dst, int* __restrict__ deg,
                             const int* __restrict__ batch, int* __restrict__ gstart,
                             int total, int N, int E, int G) {
    int idx = blockIdx.x * blockDim.x + threadIdx.x;
    if (idx >= total) return;
    xb[idx] = f2bf(x[idx]);
    if (idx < E) atomicAdd(&deg[dst[idx]], 1);
    if (idx < N) {
        int bb = batch[idx];
        if (idx == 0)
            for (int g = 0; g <= bb; g++) gstart[g] = 0;
        else {
            int pb = batch[idx - 1];
            for (int g = pb + 1; g <= bb; g++) gstart[g] = idx;
        }
        if (idx == N - 1)
            for (int g = bb + 1; g <= G; g++) gstart[g] = N;
    }
}

// single-workgroup exclusive scan of deg -> offs, cursor
__global__ __launch_bounds__(1024) void scan_kernel(const int* __restrict__ deg,
                                                    int* __restrict__ offs,
                                                    int* __restrict__ cursor, int N) {
    __shared__ int part[1024];
    int tid = threadIdx.x;
    int CH = (N + 1023) / 1024;
    int base = tid * CH;
    int s = 0;
    for (int i = 0; i < CH; i++) {
        int idx = base + i;
        if (idx < N) s += deg[idx];
    }
    part[tid] = s;
    __syncthreads();
    for (int off = 1; off < 1024; off <<= 1) {
        int v = (tid >= off) ? part[tid - off] : 0;
        __syncthreads();
        part[tid] += v;
        __syncthreads();
    }
    int run = (tid == 0) ? 0 : part[tid - 1];
    for (int i = 0; i < CH; i++) {
        int idx = base + i;
        if (idx < N) {
            offs[idx] = run;
            cursor[idx] = run;
            run += deg[idx];
        }
    }
    if (tid == 1023) offs[N] = part[1023];
}

__global__ void scatter_kernel(const int* __restrict__ src, const int* __restrict__ dst,
                               int* __restrict__ cursor, int* __restrict__ esrc, int E) {
    int e = blockIdx.x * blockDim.x + threadIdx.x;
    if (e < E) {
        int d = dst[e];
        int pos = atomicAdd(&cursor[d], 1);
        esrc[pos] = src[e];
    }
}

// ---------------- weight prep: fp32 [R][C] -> bf16 [C][R], all matrices ----
__global__ __launch_bounds__(256) void prep_kernel(const float* __restrict__ W1,
                                                   const float* __restrict__ W2,
                                                   const float* __restrict__ encW,
                                                   ushort* __restrict__ W1t,
                                                   ushort* __restrict__ W2t,
                                                   ushort* __restrict__ encWt, int L) {
    __shared__ float tile[32][33];
    int z = blockIdx.z;
    const float* in;
    ushort* out;
    int R, C;
    if (z < L) {
        in = W1 + (size_t)z * 32768; out = W1t + (size_t)z * 32768; R = 128; C = 256;
    } else if (z < 2 * L) {
        int i = z - L;
        in = W2 + (size_t)i * 32768; out = W2t + (size_t)i * 32768; R = 256; C = 128;
    } else {
        in = encW; out = encWt; R = 128; C = 128;
    }
    int r0 = blockIdx.y * 32, c0 = blockIdx.x * 32;
    if (r0 >= R || c0 >= C) return;
    int tx = threadIdx.x & 31, ty = threadIdx.x >> 5;
    for (int i = ty; i < 32; i += 8) tile[i][tx] = in[(size_t)(r0 + i) * C + c0 + tx];
    __syncthreads();
    for (int i = ty; i < 32; i += 8)
        out[(size_t)(c0 + i) * R + r0 + tx] = f2bf(tile[tx][i]);
}

// ---- aggregation: 2 nodes/wave, 4 chains, indices from LDS (staged) --------
__device__ __forceinline__ void agg_stage_v10(const ushort* __restrict__ rin,
                                              const int* __restrict__ offs,
                                              const int* __restrict__ esrc,
                                              const int* __restrict__ eidx,
                                              int ebase,
                                              const float* __restrict__ rnbuf,
                                              float tv, float sv, int row0,
                                              int w, int l, uint (*AsU)[68]) {
    int nd0 = row0 + 2 * w;
    int a0 = offs[nd0], a1 = offs[nd0 + 1], a2 = offs[nd0 + 2];
    int lo[2] = {a0 - ebase, a1 - ebase};   // LDS-relative starts
    int dg[2] = {a1 - a0, a2 - a1};
    float cs[2][4][2] = {}, cw[2][4][2] = {};
    int mx = max((dg[0] + 3) >> 2, (dg[1] + 3) >> 2);
#pragma unroll 1
    for (int i = 0; i < mx; i++) {
        int j = i * 4;
        uint rv[2][4];
        bool vl[2][4];
#pragma unroll
        for (int k = 0; k < 2; k++)
#pragma unroll
            for (int c = 0; c < 4; c++) {
                int jj = j + c;
                vl[k][c] = jj < dg[k];
                if (vl[k][c]) {
                    int off = lo[k] + jj;
                    int sn = (off < ECAP) ? eidx[off] : esrc[ebase + off];
                    rv[k][c] = ((const uint*)rin)[(size_t)sn * 64 + l];
                }
            }
#pragma unroll
        for (int k = 0; k < 2; k++)
#pragma unroll
            for (int c = 0; c < 4; c++) {
                if (vl[k][c]) {
                    float x0 = bf2f((ushort)(rv[k][c] & 0xffff));
                    float x1 = bf2f((ushort)(rv[k][c] >> 16));
                    float g0 = fmaxf(x0, 0.f) + 1e-7f;
                    float g1 = fmaxf(x1, 0.f) + 1e-7f;
                    float p0 = __expf(g0 * tv);
                    float p1 = __expf(g1 * tv);
                    cs[k][c][0] += p0;
                    cs[k][c][1] += p1;
                    cw[k][c][0] += g0 * p0;
                    cw[k][c][1] += g1 * p1;
                }
            }
    }
#pragma unroll
    for (int k = 0; k < 2; k++) {
        float s0 = (cs[k][0][0] + cs[k][1][0]) + (cs[k][2][0] + cs[k][3][0]);
        float s1 = (cs[k][0][1] + cs[k][1][1]) + (cs[k][2][1] + cs[k][3][1]);
        float W0 = (cw[k][0][0] + cw[k][1][0]) + (cw[k][2][0] + cw[k][3][0]);
        float W1 = (cw[k][0][1] + cw[k][1][1]) + (cw[k][2][1] + cw[k][3][1]);
        float agg0 = W0 / (s0 + 1e-16f);
        float agg1 = W1 / (s1 + 1e-16f);
        int nd = nd0 + k;
        float nr = sqrtf(wave_sum_f(agg0 * agg0 + agg1 * agg1));
        float fac = rnbuf[nd] * sv / fmaxf(nr, 1e-12f);
        uint ru = ((const uint*)rin)[(size_t)nd * 64 + l];
        AsU[2 * w + k][l] = f2bf2(bf2f((ushort)(ru & 0xffff)) + agg0 * fac,
                                  bf2f((ushort)(ru >> 16)) + agg1 * fac);
    }
}

// ---- gemm1 (8 waves): z1 = relu(LN256(A @ W1^T + b1)), weights prefetched --
__device__ __forceinline__ void gemm1_stage8(const ushort (*As)[136],
                                             const bf16x8 wpre[2][4],
                                             const float* __restrict__ bias,
                                             const float* __restrict__ mg,
                                             const float* __restrict__ mb,
                                             ushort (*z1s)[264],
                                             int w, int q, int ln,
                                             float (*pS)[16], float (*pQ)[16]) {
    f32x4 acc[2];
    acc[0] = (f32x4){0.f, 0.f, 0.f, 0.f};
    acc[1] = (f32x4){0.f, 0.f, 0.f, 0.f};
#pragma unroll
    for (int ks4 = 0; ks4 < 4; ks4++) {
        bf16x8 a = *(const bf16x8*)&As[ln][ks4 * 32 + q * 8];
#pragma unroll
        for (int ct = 0; ct < 2; ct++)
            acc[ct] = __builtin_amdgcn_mfma_f32_16x16x32_bf16(a, wpre[ct][ks4], acc[ct], 0, 0, 0);
    }
    float s1[4] = {0, 0, 0, 0}, s2[4] = {0, 0, 0, 0};
#pragma unroll
    for (int ct = 0; ct < 2; ct++)
#pragma unroll
        for (int r = 0; r < 4; r++) {
            float v = acc[ct][r] + bias[w * 32 + ct * 16 + ln];
            acc[ct][r] = v;
            s1[r] += v;
            s2[r] += v * v;
        }
#pragma unroll
    for (int off = 1; off < 16; off <<= 1)
#pragma unroll
        for (int r = 0; r < 4; r++) {
            s1[r] += __shfl_xor(s1[r], off, 64);
            s2[r] += __shfl_xor(s2[r], off, 64);
        }
    if (ln == 0)
#pragma unroll
        for (int r = 0; r < 4; r++) {
            pS[w][q * 4 + r] = s1[r];
            pQ[w][q * 4 + r] = s2[r];
        }
    __syncthreads();
#pragma unroll
    for (int r = 0; r < 4; r++) {
        int row = q * 4 + r;
        float S = 0.f, Q = 0.f;
#pragma unroll
        for (int ww = 0; ww < 8; ww++) {
            S += pS[ww][row];
            Q += pQ[ww][row];
        }
        float mu = S * (1.f / 256.f);
        float var = Q * (1.f / 256.f) - mu * mu;
        float rs = rsqrtf(var + 1e-5f);
#pragma unroll
        for (int ct = 0; ct < 2; ct++) {
            int col = w * 32 + ct * 16 + ln;
            float y = (acc[ct][r] - mu) * rs * mg[col] + mb[col];
            z1s[row][col] = f2bf(fmaxf(y, 0.f));
        }
    }
    __syncthreads();
}

// ---- out gemm (8 waves): v = A(16xKD)@B^T + bias (+hpre); h=v; LN128+lrelu -
template <int KD, bool RESID>
__device__ __forceinline__ void out_stage8(const ushort* __restrict__ Abase, int astr,
                                           const ushort* __restrict__ Bt,
                                           const float* __restrict__ bias,
                                           const float* __restrict__ lg,
                                           const float* __restrict__ lb,
                                           float* __restrict__ hbuf,
                                           const float* hpre,
                                           ushort* __restrict__ rout,
                                           float* __restrict__ rnbuf,
                                           int row0, int w, int q, int ln,
                                           float (*pS)[16], float (*pQ)[16]) {
    f32x4 acc = (f32x4){0.f, 0.f, 0.f, 0.f};
    int col = w * 16 + ln;
#pragma unroll
    for (int ks = 0; ks < KD; ks += 32) {
        bf16x8 a = *(const bf16x8*)(Abase + ln * astr + ks + q * 8);
        bf16x8 bv = *(const bf16x8*)(Bt + (size_t)col * KD + ks + q * 8);
        acc = __builtin_amdgcn_mfma_f32_16x16x32_bf16(a, bv, acc, 0, 0, 0);
    }
    float s1[4], s2[4];
#pragma unroll
    for (int r = 0; r < 4; r++) {
        int row = q * 4 + r;
        float v = acc[r] + bias[col];
        if (RESID) v += hpre[r];
        hbuf[(size_t)(row0 + row) * 128 + col] = v;
        acc[r] = v;
        s1[r] = v;
        s2[r] = v * v;
    }
#pragma unroll
    for (int off = 1; off < 16; off <<= 1)
#pragma unroll
        for (int r = 0; r < 4; r++) {
            s1[r] += __shfl_xor(s1[r], off, 64);
            s2[r] += __shfl_xor(s2[r], off, 64);
        }
    if (ln == 0)
#pragma unroll
        for (int r = 0; r < 4; r++) {
            pS[w][q * 4 + r] = s1[r];
            pQ[w][q * 4 + r] = s2[r];
        }
    __syncthreads();
    float yv[4];
    float t2[4];
#pragma unroll
    for (int r = 0; r < 4; r++) {
        int row = q * 4 + r;
        float S = 0.f, Q = 0.f;
#pragma unroll
        for (int ww = 0; ww < 8; ww++) {
            S += pS[ww][row];
            Q += pQ[ww][row];
        }
        float mu = S * (1.f / 128.f);
        float var = Q * (1.f / 128.f) - mu * mu;
        float rs = rsqrtf(var + 1e-5f);
        float y = (acc[r] - mu) * rs * lg[col] + lb[col];
        y = y > 0.f ? y : 0.01f * y;
        yv[r] = y;
        t2[r] = y * y;
    }
#pragma unroll
    for (int off = 1; off < 16; off <<= 1)
#pragma unroll
        for (int r = 0; r < 4; r++) t2[r] += __shfl_xor(t2[r], off, 64);
    __syncthreads();
    if (ln == 0)
#pragma unroll
        for (int r = 0; r < 4; r++) pS[w][q * 4 + r] = t2[r];
    __syncthreads();
#pragma unroll
    for (int r = 0; r < 4; r++) {
        int row = q * 4 + r;
        float T = 0.f;
#pragma unroll
        for (int ww = 0; ww < 8; ww++) T += pS[ww][row];
        if (w == 0 && ln == 0) rnbuf[row0 + row] = sqrtf(T);
        rout[(size_t)(row0 + row) * 128 + col] = f2bf(yv[r]);
    }
}

// ---------------- encoder: h = xb @ encW^T + b; LN0 + lrelu ----------------
__global__ __launch_bounds__(BT) void enc_kernel(const ushort* __restrict__ xb,
                                                 const ushort* __restrict__ encWt,
                                                 const float* __restrict__ encB,
                                                 const float* __restrict__ lg,
                                                 const float* __restrict__ lb,
                                                 float* __restrict__ h,
                                                 ushort* __restrict__ r,
                                                 float* __restrict__ rn, int N) {
    __shared__ __align__(16) ushort As[16][136];
    __shared__ float pS[8][16], pQ[8][16];
    uint(*AsU)[68] = (uint(*)[68])As;
    int tid = threadIdx.x, w = tid >> 6, l = tid & 63;
    int q = l >> 4, ln = l & 15;
    int row0 = blockIdx.x * 16;
    for (int idx = tid; idx < 16 * 64; idx += BT) {
        int row = idx >> 6, cl = idx & 63;
        AsU[row][cl] = ((const uint*)xb)[(size_t)(row0 + row) * 64 + cl];
    }
    __syncthreads();
    out_stage8<128, false>(&As[0][0], 136, encWt, encB, lg, lb, h, nullptr, r, rn,
                           row0, w, q, ln, pS, pQ);
}

// ---------------- fused layer: 16-row tile, agg + gemm1 + gemm2 ------------
__global__ __launch_bounds__(BT) void layer_kernel(const ushort* __restrict__ rin,
                                                   ushort* __restrict__ rout,
                                                   const int* __restrict__ offs,
                                                   const int* __restrict__ esrc,
                                                   float* __restrict__ rn,
                                                   float* __restrict__ h,
                                                   const ushort* __restrict__ W1t,
                                                   const ushort* __restrict__ W2t,
                                                   const float* __restrict__ b1,
                                                   const float* __restrict__ mg,
                                                   const float* __restrict__ mb,
                                                   const float* __restrict__ b2,
                                                   const float* __restrict__ ng,
                                                   const float* __restrict__ nb,
                                                   const float* __restrict__ tptr,
                                                   const float* __restrict__ scptr,
                                                   int N) {
    __shared__ __align__(16) ushort As[16][136];
    __shared__ __align__(16) ushort z1s[16][264];
    __shared__ float pS[8][16], pQ[8][16];
    __shared__ int eidx[ECAP];
    uint(*AsU)[68] = (uint(*)[68])As;
    int tid = threadIdx.x, w = tid >> 6, l = tid & 63;
    int q = l >> 4, ln = l & 15;
    int row0 = blockIdx.x * 16;
    float tv = *tptr, sv = *scptr;

    // prefetch gemm1 weight fragments (overlaps agg's gather latency)
    bf16x8 wpre[2][4];
#pragma unroll
    for (int ct = 0; ct < 2; ct++)
#pragma unroll
        for (int ks4 = 0; ks4 < 4; ks4++)
            wpre[ct][ks4] = *(const bf16x8*)(W1t + (size_t)(w * 32 + ct * 16 + ln) * 128 + ks4 * 32 + q * 8);

    // prefetch residual h values for out stage
    float hpre[4];
    {
        int col = w * 16 + ln;
#pragma unroll
        for (int r = 0; r < 4; r++)
            hpre[r] = h[(size_t)(row0 + q * 4 + r) * 128 + col];
    }

    // stage this block's CSR edge-index segment into LDS (coalesced)
    int ebase = offs[row0];
    int ecnt = offs[row0 + 16] - ebase;
    int ecap = min(ecnt, ECAP);
    for (int i = tid; i < ecap; i += BT) eidx[i] = esrc[ebase + i];
    __syncthreads();

    agg_stage_v10(rin, offs, esrc, eidx, ebase, rn, tv, sv, row0, w, l, AsU);
    __syncthreads();
    gemm1_stage8(As, wpre, b1, mg, mb, z1s, w, q, ln, pS, pQ);
    out_stage8<256, true>(&z1s[0][0], 264, W2t, b2, ng, nb, h, hpre, rout, rn,
                          row0, w, q, ln, pS, pQ);
}

// ---------------- pool: one block per graph, 4 waves over rows -------------
__global__ __launch_bounds__(256) void pool_kernel(const ushort* __restrict__ rf,
                                                   const int* __restrict__ gstart,
                                                   float* __restrict__ out) {
    __shared__ float pb0[4][64], pb1[4][64];
    int g = blockIdx.x;
    int w = threadIdx.x >> 6, l = threadIdx.x & 63;
    int s = gstart[g], e = gstart[g + 1];
    float a0 = 0.f, a1 = 0.f;
    for (int n = s + w; n < e; n += 4) {
        uint rv = ((const uint*)rf)[(size_t)n * 64 + l];
        a0 += bf2f((ushort)(rv & 0xffff));
        a1 += bf2f((ushort)(rv >> 16));
    }
    pb0[w][l] = a0;
    pb1[w][l] = a1;
    __syncthreads();
    if (threadIdx.x < 64) {
        float t0 = pb0[0][l] + pb0[1][l] + pb0[2][l] + pb0[3][l];
        float t1 = pb1[0][l] + pb1[1][l] + pb1[2][l] + pb1[3][l];
        float inv = 1.f / fmaxf((float)(e - s), 1.f);
        out[g * 128 + 2 * l] = t0 * inv;
        out[g * 128 + 2 * l + 1] = t1 * inv;
    }
}

// ---------------------------------------------------------------------------
extern "C" void kernel_launch(void* const* d_in, const int* in_sizes, int n_in,
                              void* d_out, int out_size, void* d_ws, size_t ws_size,
                              hipStream_t stream) {
    const float* x     = (const float*)d_in[0];
    const int*   ei    = (const int*)d_in[1];
    const int*   batch = (const int*)d_in[2];
    const float* encW  = (const float*)d_in[3];
    const float* encB  = (const float*)d_in[4];
    const float* ln_g  = (const float*)d_in[5];
    const float* ln_b  = (const float*)d_in[6];
    const float* tArr  = (const float*)d_in[7];
    const float* scArr = (const float*)d_in[8];
    const float* W1    = (const float*)d_in[9];
    const float* b1    = (const float*)d_in[10];
    const float* mg    = (const float*)d_in[11];
    const float* mb    = (const float*)d_in[12];
    const float* W2    = (const float*)d_in[13];
    const float* b2    = (const float*)d_in[14];
    const float* fn_g  = (const float*)d_in[15];
    const float* fn_b  = (const float*)d_in[16];
    float* out = (float*)d_out;

    const int N = in_sizes[0] / 128;  // 10000
    const int E = in_sizes[1] / 2;    // 160000
    const int L = in_sizes[7];        // 14
    const int G = 64;

    const int* src = ei;
    const int* dst = ei + E;

    char* p = (char*)d_ws;
    auto alloc = [&](size_t bytes) -> void* {
        void* qp = (void*)p;
        p += (bytes + 255) & ~(size_t)255;
        return qp;
    };
    int*    deg    = (int*)alloc((size_t)N * 4);
    int*    offs   = (int*)alloc((size_t)(N + 1) * 4);
    int*    cursor = (int*)alloc((size_t)N * 4);
    int*    esrc   = (int*)alloc((size_t)E * 4);
    int*    gstart = (int*)alloc((size_t)(G + 1) * 4);
    float*  h      = (float*)alloc((size_t)N * 128 * 4);
    ushort* r0     = (ushort*)alloc((size_t)N * 128 * 2);
    ushort* r1     = (ushort*)alloc((size_t)N * 128 * 2);
    float*  rn     = (float*)alloc((size_t)N * 4);
    ushort* xb     = (ushort*)alloc((size_t)N * 128 * 2);
    ushort* W1t    = (ushort*)alloc((size_t)L * 32768 * 2);
    ushort* W2t    = (ushort*)alloc((size_t)L * 32768 * 2);
    ushort* encWt  = (ushort*)alloc((size_t)16384 * 2);

    hipMemsetAsync(deg, 0, (size_t)N * 4, stream);

    setup_kernel<<<(N * 128 + 255) / 256, 256, 0, stream>>>(x, xb, dst, deg, batch,
                                                            gstart, N * 128, N, E, G);
    scan_kernel<<<1, 1024, 0, stream>>>(deg, offs, cursor, N);
    scatter_kernel<<<(E + 255) / 256, 256, 0, stream>>>(src, dst, cursor, esrc, E);
    prep_kernel<<<dim3(8, 8, 2 * L + 1), 256, 0, stream>>>(W1, W2, encW, W1t, W2t,
                                                           encWt, L);

    const int TILES = N / 16;  // 625

    enc_kernel<<<TILES, BT, 0, stream>>>(xb, encWt, encB, ln_g, ln_b, h, r0, rn, N);

    for (int i = 0; i < L; i++) {
        const ushort* rin = (i & 1) ? r1 : r0;
        ushort* rout = (i & 1) ? r0 : r1;
        const float* ng = (i < L - 1) ? (ln_g + (size_t)(i + 1) * 128) : fn_g;
        const float* nb = (i < L - 1) ? (ln_b + (size_t)(i + 1) * 128) : fn_b;
        layer_kernel<<<TILES, BT, 0, stream>>>(rin, rout, offs, esrc, rn, h,
                                               W1t + ((size_t)i << 15),
                                               W2t + ((size_t)i << 15),
                                               b1 + (size_t)i * 256,
                                               mg + (size_t)i * 256,
                                               mb + (size_t)i * 256,
                                               b2 + (size_t)i * 128,
                                               ng, nb, tArr + i, scArr + i, N);
    }

    // last layer i=L-1 wrote rout = ((L-1)&1) ? r0 : r1
    const ushort* rf = ((L - 1) & 1) ? r0 : r1;
    pool_kernel<<<G, 256, 0, stream>>>(rf, gstart, out);
}

// Round 12
// 724.156 us; speedup vs baseline: 1.0973x; 1.0973x over previous
//
#include <hip/hip_runtime.h>
#include <cstdint>
#include <cstddef>

// ---------------------------------------------------------------------------
// DeeperGCN forward on MI355X. Round 12 (= round 11 + compile fix: enc_kernel
// output pointer was shadowed by a loop variable). SPLIT layer: agg_kernel =
// 2500 blocks x 256 thr, 1 node/wave, 4 chains, no LDS/barriers; mlp_kernel =
// 313 blocks x 512 thr, 32-row tiles.
// N=10000 nodes, E=160000 edges, H=128, L=14 layers, G=64 graphs.
// ---------------------------------------------------------------------------

typedef __attribute__((ext_vector_type(8))) short bf16x8;
typedef __attribute__((ext_vector_type(4))) float f32x4;

__device__ inline float bf2f(ushort u) {
    union { uint i; float f; } v;
    v.i = (uint)u << 16;
    return v.f;
}
__device__ inline ushort f2bf(float f) {
    union { float f; uint i; } v;
    v.f = f;
    return (ushort)((v.i + 0x7fffu + ((v.i >> 16) & 1u)) >> 16);
}
__device__ inline uint f2bf2(float a, float b) {
    return (uint)f2bf(a) | ((uint)f2bf(b) << 16);
}

__device__ inline float wave_sum_f(float v) {
#pragma unroll
    for (int off = 32; off > 0; off >>= 1) v += __shfl_xor(v, off, 64);
    return v;
}

// ---------------- setup: xb convert + deg histogram + graph boundaries -----
__global__ void setup_kernel(const float* __restrict__ x, ushort* __restrict__ xb,
                             const int* __restrict__ dst, int* __restrict__ deg,
                             const int* __restrict__ batch, int* __restrict__ gstart,
                             int total, int N, int E, int G) {
    int idx = blockIdx.x * blockDim.x + threadIdx.x;
    if (idx >= total) return;
    xb[idx] = f2bf(x[idx]);
    if (idx < E) atomicAdd(&deg[dst[idx]], 1);
    if (idx < N) {
        int bb = batch[idx];
        if (idx == 0)
            for (int g = 0; g <= bb; g++) gstart[g] = 0;
        else {
            int pb = batch[idx - 1];
            for (int g = pb + 1; g <= bb; g++) gstart[g] = idx;
        }
        if (idx == N - 1)
            for (int g = bb + 1; g <= G; g++) gstart[g] = N;
    }
}

// single-workgroup exclusive scan of deg -> offs, cursor
__global__ __launch_bounds__(1024) void scan_kernel(const int* __restrict__ deg,
                                                    int* __restrict__ offs,
                                                    int* __restrict__ cursor, int N) {
    __shared__ int part[1024];
    int tid = threadIdx.x;
    int CH = (N + 1023) / 1024;
    int base = tid * CH;
    int s = 0;
    for (int i = 0; i < CH; i++) {
        int idx = base + i;
        if (idx < N) s += deg[idx];
    }
    part[tid] = s;
    __syncthreads();
    for (int off = 1; off < 1024; off <<= 1) {
        int v = (tid >= off) ? part[tid - off] : 0;
        __syncthreads();
        part[tid] += v;
        __syncthreads();
    }
    int run = (tid == 0) ? 0 : part[tid - 1];
    for (int i = 0; i < CH; i++) {
        int idx = base + i;
        if (idx < N) {
            offs[idx] = run;
            cursor[idx] = run;
            run += deg[idx];
        }
    }
    if (tid == 1023) offs[N] = part[1023];
}

__global__ void scatter_kernel(const int* __restrict__ src, const int* __restrict__ dst,
                               int* __restrict__ cursor, int* __restrict__ esrc, int E) {
    int e = blockIdx.x * blockDim.x + threadIdx.x;
    if (e < E) {
        int d = dst[e];
        int pos = atomicAdd(&cursor[d], 1);
        esrc[pos] = src[e];
    }
}

// ---------------- weight prep: fp32 [R][C] -> bf16 [C][R], all matrices ----
__global__ __launch_bounds__(256) void prep_kernel(const float* __restrict__ W1,
                                                   const float* __restrict__ W2,
                                                   const float* __restrict__ encW,
                                                   ushort* __restrict__ W1t,
                                                   ushort* __restrict__ W2t,
                                                   ushort* __restrict__ encWt, int L) {
    __shared__ float tile[32][33];
    int z = blockIdx.z;
    const float* in;
    ushort* out;
    int R, C;
    if (z < L) {
        in = W1 + (size_t)z * 32768; out = W1t + (size_t)z * 32768; R = 128; C = 256;
    } else if (z < 2 * L) {
        int i = z - L;
        in = W2 + (size_t)i * 32768; out = W2t + (size_t)i * 32768; R = 256; C = 128;
    } else {
        in = encW; out = encWt; R = 128; C = 128;
    }
    int r0 = blockIdx.y * 32, c0 = blockIdx.x * 32;
    if (r0 >= R || c0 >= C) return;
    int tx = threadIdx.x & 31, ty = threadIdx.x >> 5;
    for (int i = ty; i < 32; i += 8) tile[i][tx] = in[(size_t)(r0 + i) * C + c0 + tx];
    __syncthreads();
    for (int i = ty; i < 32; i += 8)
        out[(size_t)(c0 + i) * R + r0 + tx] = f2bf(tile[tx][i]);
}

// ---------------- agg: standalone, 1 node/wave, 4 chains, max-free softmax --
__global__ __launch_bounds__(256) void agg_kernel(const ushort* __restrict__ rin,
                                                  ushort* __restrict__ u,
                                                  const int* __restrict__ offs,
                                                  const int* __restrict__ esrc,
                                                  const float* __restrict__ rnbuf,
                                                  const float* __restrict__ tptr,
                                                  const float* __restrict__ scptr,
                                                  int N) {
    int w = threadIdx.x >> 6, l = threadIdx.x & 63;
    int nd = blockIdx.x * 4 + w;
    if (nd >= N) return;
    float tv = *tptr, sv = *scptr;
    int e0 = offs[nd];
    int deg = offs[nd + 1] - e0;
    float cs[4][2] = {{0.f, 0.f}, {0.f, 0.f}, {0.f, 0.f}, {0.f, 0.f}};
    float cw[4][2] = {{0.f, 0.f}, {0.f, 0.f}, {0.f, 0.f}, {0.f, 0.f}};
    int it = (deg + 3) >> 2;
#pragma unroll 1
    for (int i = 0; i < it; i++) {
        int j = i * 4;
        uint rv[4];
        bool vl[4];
#pragma unroll
        for (int c = 0; c < 4; c++) {
            vl[c] = (j + c) < deg;
            if (vl[c]) {
                int sn = esrc[e0 + j + c];
                rv[c] = ((const uint*)rin)[(size_t)sn * 64 + l];
            }
        }
#pragma unroll
        for (int c = 0; c < 4; c++) {
            if (vl[c]) {
                float x0 = bf2f((ushort)(rv[c] & 0xffff));
                float x1 = bf2f((ushort)(rv[c] >> 16));
                float g0 = fmaxf(x0, 0.f) + 1e-7f;
                float g1 = fmaxf(x1, 0.f) + 1e-7f;
                float p0 = __expf(g0 * tv);
                float p1 = __expf(g1 * tv);
                cs[c][0] += p0;
                cs[c][1] += p1;
                cw[c][0] += g0 * p0;
                cw[c][1] += g1 * p1;
            }
        }
    }
    float s0 = (cs[0][0] + cs[1][0]) + (cs[2][0] + cs[3][0]);
    float s1 = (cs[0][1] + cs[1][1]) + (cs[2][1] + cs[3][1]);
    float W0 = (cw[0][0] + cw[1][0]) + (cw[2][0] + cw[3][0]);
    float W1 = (cw[0][1] + cw[1][1]) + (cw[2][1] + cw[3][1]);
    float agg0 = W0 / (s0 + 1e-16f);
    float agg1 = W1 / (s1 + 1e-16f);
    float nr = sqrtf(wave_sum_f(agg0 * agg0 + agg1 * agg1));
    float fac = rnbuf[nd] * sv / fmaxf(nr, 1e-12f);
    uint ru = ((const uint*)rin)[(size_t)nd * 64 + l];
    ((uint*)u)[(size_t)nd * 64 + l] = f2bf2(bf2f((ushort)(ru & 0xffff)) + agg0 * fac,
                                            bf2f((ushort)(ru >> 16)) + agg1 * fac);
}

// ---------------- mlp: 32-row tile, gemm1(LN256,relu) + gemm2(resid,LN128) --
__global__ __launch_bounds__(512) void mlp_kernel(const ushort* __restrict__ u,
                                                  ushort* __restrict__ rout,
                                                  float* __restrict__ h,
                                                  const ushort* __restrict__ W1t,
                                                  const ushort* __restrict__ W2t,
                                                  const float* __restrict__ b1,
                                                  const float* __restrict__ mg,
                                                  const float* __restrict__ mb,
                                                  const float* __restrict__ b2,
                                                  const float* __restrict__ ng,
                                                  const float* __restrict__ nb,
                                                  float* __restrict__ rn, int N) {
    __shared__ __align__(16) ushort As[32][136];
    __shared__ __align__(16) ushort z1s[32][264];
    __shared__ float pS[8][32], pQ[8][32];
    uint(*AsU)[68] = (uint(*)[68])As;
    int tid = threadIdx.x, w = tid >> 6, l = tid & 63;
    int q = l >> 4, ln = l & 15;
    int row0 = blockIdx.x * 32;

    for (int idx = tid; idx < 32 * 64; idx += 512) {
        int row = idx >> 6, cl = idx & 63;
        uint v = 0;
        if (row0 + row < N) v = ((const uint*)u)[(size_t)(row0 + row) * 64 + cl];
        AsU[row][cl] = v;
    }
    __syncthreads();

    // ---- gemm1 ----
    f32x4 acc[2][2];
#pragma unroll
    for (int rt = 0; rt < 2; rt++)
#pragma unroll
        for (int ct = 0; ct < 2; ct++) acc[rt][ct] = (f32x4){0.f, 0.f, 0.f, 0.f};
#pragma unroll
    for (int ks = 0; ks < 128; ks += 32) {
        bf16x8 a[2];
#pragma unroll
        for (int rt = 0; rt < 2; rt++) a[rt] = *(const bf16x8*)&As[rt * 16 + ln][ks + q * 8];
#pragma unroll
        for (int ct = 0; ct < 2; ct++) {
            bf16x8 bv = *(const bf16x8*)(W1t + (size_t)(w * 32 + ct * 16 + ln) * 128 + ks + q * 8);
#pragma unroll
            for (int rt = 0; rt < 2; rt++)
                acc[rt][ct] = __builtin_amdgcn_mfma_f32_16x16x32_bf16(a[rt], bv, acc[rt][ct], 0, 0, 0);
        }
    }
    float s1[2][4] = {}, s2[2][4] = {};
#pragma unroll
    for (int rt = 0; rt < 2; rt++)
#pragma unroll
        for (int ct = 0; ct < 2; ct++)
#pragma unroll
            for (int r = 0; r < 4; r++) {
                float v = acc[rt][ct][r] + b1[w * 32 + ct * 16 + ln];
                acc[rt][ct][r] = v;
                s1[rt][r] += v;
                s2[rt][r] += v * v;
            }
#pragma unroll
    for (int off = 1; off < 16; off <<= 1)
#pragma unroll
        for (int rt = 0; rt < 2; rt++)
#pragma unroll
            for (int r = 0; r < 4; r++) {
                s1[rt][r] += __shfl_xor(s1[rt][r], off, 64);
                s2[rt][r] += __shfl_xor(s2[rt][r], off, 64);
            }
    if (ln == 0)
#pragma unroll
        for (int rt = 0; rt < 2; rt++)
#pragma unroll
            for (int r = 0; r < 4; r++) {
                pS[w][rt * 16 + q * 4 + r] = s1[rt][r];
                pQ[w][rt * 16 + q * 4 + r] = s2[rt][r];
            }
    __syncthreads();
#pragma unroll
    for (int rt = 0; rt < 2; rt++)
#pragma unroll
        for (int r = 0; r < 4; r++) {
            int row = rt * 16 + q * 4 + r;
            float S = 0.f, Q = 0.f;
#pragma unroll
            for (int ww = 0; ww < 8; ww++) {
                S += pS[ww][row];
                Q += pQ[ww][row];
            }
            float mu = S * (1.f / 256.f);
            float var = Q * (1.f / 256.f) - mu * mu;
            float rs = rsqrtf(var + 1e-5f);
#pragma unroll
            for (int ct = 0; ct < 2; ct++) {
                int col = w * 32 + ct * 16 + ln;
                float y = (acc[rt][ct][r] - mu) * rs * mg[col] + mb[col];
                z1s[row][col] = f2bf(fmaxf(y, 0.f));
            }
        }
    __syncthreads();

    // ---- gemm2 ----
    int col = w * 16 + ln;
    f32x4 acc2[2];
    acc2[0] = (f32x4){0.f, 0.f, 0.f, 0.f};
    acc2[1] = (f32x4){0.f, 0.f, 0.f, 0.f};
#pragma unroll
    for (int ks = 0; ks < 256; ks += 32) {
        bf16x8 bv = *(const bf16x8*)(W2t + (size_t)col * 256 + ks + q * 8);
#pragma unroll
        for (int rt = 0; rt < 2; rt++) {
            bf16x8 a = *(const bf16x8*)&z1s[rt * 16 + ln][ks + q * 8];
            acc2[rt] = __builtin_amdgcn_mfma_f32_16x16x32_bf16(a, bv, acc2[rt], 0, 0, 0);
        }
    }
    float t1[2][4], t2[2][4];
#pragma unroll
    for (int rt = 0; rt < 2; rt++)
#pragma unroll
        for (int r = 0; r < 4; r++) {
            int row = rt * 16 + q * 4 + r;
            int grow = row0 + row;
            float v = acc2[rt][r] + b2[col];
            if (grow < N) {
                v += h[(size_t)grow * 128 + col];
                h[(size_t)grow * 128 + col] = v;
            }
            acc2[rt][r] = v;
            t1[rt][r] = v;
            t2[rt][r] = v * v;
        }
#pragma unroll
    for (int off = 1; off < 16; off <<= 1)
#pragma unroll
        for (int rt = 0; rt < 2; rt++)
#pragma unroll
            for (int r = 0; r < 4; r++) {
                t1[rt][r] += __shfl_xor(t1[rt][r], off, 64);
                t2[rt][r] += __shfl_xor(t2[rt][r], off, 64);
            }
    if (ln == 0)
#pragma unroll
        for (int rt = 0; rt < 2; rt++)
#pragma unroll
            for (int r = 0; r < 4; r++) {
                pS[w][rt * 16 + q * 4 + r] = t1[rt][r];
                pQ[w][rt * 16 + q * 4 + r] = t2[rt][r];
            }
    __syncthreads();
    float yv[2][4];
    float n2[2][4];
#pragma unroll
    for (int rt = 0; rt < 2; rt++)
#pragma unroll
        for (int r = 0; r < 4; r++) {
            int row = rt * 16 + q * 4 + r;
            float S = 0.f, Q = 0.f;
#pragma unroll
            for (int ww = 0; ww < 8; ww++) {
                S += pS[ww][row];
                Q += pQ[ww][row];
            }
            float mu = S * (1.f / 128.f);
            float var = Q * (1.f / 128.f) - mu * mu;
            float rs = rsqrtf(var + 1e-5f);
            float y = (acc2[rt][r] - mu) * rs * ng[col] + nb[col];
            y = y > 0.f ? y : 0.01f * y;
            yv[rt][r] = y;
            n2[rt][r] = y * y;
        }
#pragma unroll
    for (int off = 1; off < 16; off <<= 1)
#pragma unroll
        for (int rt = 0; rt < 2; rt++)
#pragma unroll
            for (int r = 0; r < 4; r++) n2[rt][r] += __shfl_xor(n2[rt][r], off, 64);
    __syncthreads();
    if (ln == 0)
#pragma unroll
        for (int rt = 0; rt < 2; rt++)
#pragma unroll
            for (int r = 0; r < 4; r++) pS[w][rt * 16 + q * 4 + r] = n2[rt][r];
    __syncthreads();
#pragma unroll
    for (int rt = 0; rt < 2; rt++)
#pragma unroll
        for (int r = 0; r < 4; r++) {
            int row = rt * 16 + q * 4 + r;
            int grow = row0 + row;
            if (grow >= N) continue;
            float T = 0.f;
#pragma unroll
            for (int ww = 0; ww < 8; ww++) T += pS[ww][row];
            if (w == 0 && ln == 0) rn[grow] = sqrtf(T);
            rout[(size_t)grow * 128 + col] = f2bf(yv[rt][r]);
        }
}

// ---------------- encoder: h = xb @ encW^T + b; LN0 + lrelu (16-row) -------
__global__ __launch_bounds__(512) void enc_kernel(const ushort* __restrict__ xb,
                                                  const ushort* __restrict__ encWt,
                                                  const float* __restrict__ encB,
                                                  const float* __restrict__ lg,
                                                  const float* __restrict__ lb,
                                                  float* __restrict__ h,
                                                  ushort* __restrict__ rout,
                                                  float* __restrict__ rn, int N) {
    __shared__ __align__(16) ushort As[16][136];
    __shared__ float pS[8][16], pQ[8][16];
    uint(*AsU)[68] = (uint(*)[68])As;
    int tid = threadIdx.x, w = tid >> 6, l = tid & 63;
    int q = l >> 4, ln = l & 15;
    int row0 = blockIdx.x * 16;
    for (int idx = tid; idx < 16 * 64; idx += 512) {
        int row = idx >> 6, cl = idx & 63;
        AsU[row][cl] = ((const uint*)xb)[(size_t)(row0 + row) * 64 + cl];
    }
    __syncthreads();
    int col = w * 16 + ln;
    f32x4 acc = (f32x4){0.f, 0.f, 0.f, 0.f};
#pragma unroll
    for (int ks = 0; ks < 128; ks += 32) {
        bf16x8 a = *(const bf16x8*)&As[ln][ks + q * 8];
        bf16x8 bv = *(const bf16x8*)(encWt + (size_t)col * 128 + ks + q * 8);
        acc = __builtin_amdgcn_mfma_f32_16x16x32_bf16(a, bv, acc, 0, 0, 0);
    }
    float s1[4], s2[4];
#pragma unroll
    for (int r = 0; r < 4; r++) {
        int row = q * 4 + r;
        float v = acc[r] + encB[col];
        h[(size_t)(row0 + row) * 128 + col] = v;
        acc[r] = v;
        s1[r] = v;
        s2[r] = v * v;
    }
#pragma unroll
    for (int off = 1; off < 16; off <<= 1)
#pragma unroll
        for (int r = 0; r < 4; r++) {
            s1[r] += __shfl_xor(s1[r], off, 64);
            s2[r] += __shfl_xor(s2[r], off, 64);
        }
    if (ln == 0)
#pragma unroll
        for (int r = 0; r < 4; r++) {
            pS[w][q * 4 + r] = s1[r];
            pQ[w][q * 4 + r] = s2[r];
        }
    __syncthreads();
    float yv[4], t2[4];
#pragma unroll
    for (int r = 0; r < 4; r++) {
        int row = q * 4 + r;
        float S = 0.f, Q = 0.f;
#pragma unroll
        for (int ww = 0; ww < 8; ww++) {
            S += pS[ww][row];
            Q += pQ[ww][row];
        }
        float mu = S * (1.f / 128.f);
        float var = Q * (1.f / 128.f) - mu * mu;
        float rs = rsqrtf(var + 1e-5f);
        float y = (acc[r] - mu) * rs * lg[col] + lb[col];
        y = y > 0.f ? y : 0.01f * y;
        yv[r] = y;
        t2[r] = y * y;
    }
#pragma unroll
    for (int off = 1; off < 16; off <<= 1)
#pragma unroll
        for (int r = 0; r < 4; r++) t2[r] += __shfl_xor(t2[r], off, 64);
    __syncthreads();
    if (ln == 0)
#pragma unroll
        for (int r = 0; r < 4; r++) pS[w][q * 4 + r] = t2[r];
    __syncthreads();
#pragma unroll
    for (int r = 0; r < 4; r++) {
        int row = q * 4 + r;
        float T = 0.f;
#pragma unroll
        for (int ww = 0; ww < 8; ww++) T += pS[ww][row];
        if (w == 0 && ln == 0) rn[row0 + row] = sqrtf(T);
        rout[(size_t)(row0 + row) * 128 + col] = f2bf(yv[r]);
    }
}

// ---------------- pool: one block per graph, 4 waves over rows -------------
__global__ __launch_bounds__(256) void pool_kernel(const ushort* __restrict__ rf,
                                                   const int* __restrict__ gstart,
                                                   float* __restrict__ out) {
    __shared__ float pb0[4][64], pb1[4][64];
    int g = blockIdx.x;
    int w = threadIdx.x >> 6, l = threadIdx.x & 63;
    int s = gstart[g], e = gstart[g + 1];
    float a0 = 0.f, a1 = 0.f;
    for (int n = s + w; n < e; n += 4) {
        uint rv = ((const uint*)rf)[(size_t)n * 64 + l];
        a0 += bf2f((ushort)(rv & 0xffff));
        a1 += bf2f((ushort)(rv >> 16));
    }
    pb0[w][l] = a0;
    pb1[w][l] = a1;
    __syncthreads();
    if (threadIdx.x < 64) {
        float t0 = pb0[0][l] + pb0[1][l] + pb0[2][l] + pb0[3][l];
        float t1 = pb1[0][l] + pb1[1][l] + pb1[2][l] + pb1[3][l];
        float inv = 1.f / fmaxf((float)(e - s), 1.f);
        out[g * 128 + 2 * l] = t0 * inv;
        out[g * 128 + 2 * l + 1] = t1 * inv;
    }
}

// ---------------------------------------------------------------------------
extern "C" void kernel_launch(void* const* d_in, const int* in_sizes, int n_in,
                              void* d_out, int out_size, void* d_ws, size_t ws_size,
                              hipStream_t stream) {
    const float* x     = (const float*)d_in[0];
    const int*   ei    = (const int*)d_in[1];
    const int*   batch = (const int*)d_in[2];
    const float* encW  = (const float*)d_in[3];
    const float* encB  = (const float*)d_in[4];
    const float* ln_g  = (const float*)d_in[5];
    const float* ln_b  = (const float*)d_in[6];
    const float* tArr  = (const float*)d_in[7];
    const float* scArr = (const float*)d_in[8];
    const float* W1    = (const float*)d_in[9];
    const float* b1    = (const float*)d_in[10];
    const float* mg    = (const float*)d_in[11];
    const float* mb    = (const float*)d_in[12];
    const float* W2    = (const float*)d_in[13];
    const float* b2    = (const float*)d_in[14];
    const float* fn_g  = (const float*)d_in[15];
    const float* fn_b  = (const float*)d_in[16];
    float* out = (float*)d_out;

    const int N = in_sizes[0] / 128;  // 10000
    const int E = in_sizes[1] / 2;    // 160000
    const int L = in_sizes[7];        // 14
    const int G = 64;

    const int* src = ei;
    const int* dst = ei + E;

    char* p = (char*)d_ws;
    auto alloc = [&](size_t bytes) -> void* {
        void* qp = (void*)p;
        p += (bytes + 255) & ~(size_t)255;
        return qp;
    };
    int*    deg    = (int*)alloc((size_t)N * 4);
    int*    offs   = (int*)alloc((size_t)(N + 1) * 4);
    int*    cursor = (int*)alloc((size_t)N * 4);
    int*    esrc   = (int*)alloc((size_t)E * 4);
    int*    gstart = (int*)alloc((size_t)(G + 1) * 4);
    float*  h      = (float*)alloc((size_t)N * 128 * 4);
    ushort* r0     = (ushort*)alloc((size_t)N * 128 * 2);
    ushort* r1     = (ushort*)alloc((size_t)N * 128 * 2);
    ushort* u      = (ushort*)alloc((size_t)N * 128 * 2);
    float*  rn     = (float*)alloc((size_t)N * 4);
    ushort* xb     = (ushort*)alloc((size_t)N * 128 * 2);
    ushort* W1t    = (ushort*)alloc((size_t)L * 32768 * 2);
    ushort* W2t    = (ushort*)alloc((size_t)L * 32768 * 2);
    ushort* encWt  = (ushort*)alloc((size_t)16384 * 2);

    (void)hipMemsetAsync(deg, 0, (size_t)N * 4, stream);

    setup_kernel<<<(N * 128 + 255) / 256, 256, 0, stream>>>(x, xb, dst, deg, batch,
                                                            gstart, N * 128, N, E, G);
    scan_kernel<<<1, 1024, 0, stream>>>(deg, offs, cursor, N);
    scatter_kernel<<<(E + 255) / 256, 256, 0, stream>>>(src, dst, cursor, esrc, E);
    prep_kernel<<<dim3(8, 8, 2 * L + 1), 256, 0, stream>>>(W1, W2, encW, W1t, W2t,
                                                           encWt, L);

    enc_kernel<<<N / 16, 512, 0, stream>>>(xb, encWt, encB, ln_g, ln_b, h, r0, rn, N);

    const int AGGB = (N + 3) / 4;    // 2500
    const int MLPB = (N + 31) / 32;  // 313

    for (int i = 0; i < L; i++) {
        const ushort* rin = (i & 1) ? r1 : r0;
        ushort* rout = (i & 1) ? r0 : r1;
        const float* ng = (i < L - 1) ? (ln_g + (size_t)(i + 1) * 128) : fn_g;
        const float* nb = (i < L - 1) ? (ln_b + (size_t)(i + 1) * 128) : fn_b;
        agg_kernel<<<AGGB, 256, 0, stream>>>(rin, u, offs, esrc, rn,
                                             tArr + i, scArr + i, N);
        mlp_kernel<<<MLPB, 512, 0, stream>>>(u, rout, h,
                                             W1t + ((size_t)i << 15),
                                             W2t + ((size_t)i << 15),
                                             b1 + (size_t)i * 256,
                                             mg + (size_t)i * 256,
                                             mb + (size_t)i * 256,
                                             b2 + (size_t)i * 128,
                                             ng, nb, rn, N);
    }

    // last layer i=L-1 wrote rout = ((L-1)&1) ? r0 : r1
    const ushort* rf = ((L - 1) & 1) ? r0 : r1;
    pool_kernel<<<G, 256, 0, stream>>>(rf, gstart, out);
}

// Round 13
// 585.657 us; speedup vs baseline: 1.3568x; 1.2365x over previous
//
#include <hip/hip_runtime.h>
#include <cstdint>
#include <cstddef>

// ---------------------------------------------------------------------------
// DeeperGCN forward on MI355X. Round 13: round 9 (fused 16-row layer, best
// 664 us) with the gather phase re-engineered: (1) wave-parallel index
// preload (one vector load grabs all <=64 edge indices; loop uses __shfl),
// (2) half-wave uint2 gathers (lanes 0-31 fetch edge A, 32-63 edge B in one
// instruction -> 8 edges in flight/node, iterations = ceil(deg/8)). Halves
// merge with shfl_xor(32) adds (max-free softmax is associative).
// N=10000 nodes, E=160000 edges, H=128, L=14 layers, G=64 graphs.
// ---------------------------------------------------------------------------

#define BT 512  // 8 waves

typedef __attribute__((ext_vector_type(8))) short bf16x8;
typedef __attribute__((ext_vector_type(4))) float f32x4;

__device__ inline float bf2f(ushort u) {
    union { uint i; float f; } v;
    v.i = (uint)u << 16;
    return v.f;
}
__device__ inline ushort f2bf(float f) {
    union { float f; uint i; } v;
    v.f = f;
    return (ushort)((v.i + 0x7fffu + ((v.i >> 16) & 1u)) >> 16);
}
__device__ inline uint f2bf2(float a, float b) {
    return (uint)f2bf(a) | ((uint)f2bf(b) << 16);
}

__device__ inline float wave_sum_f(float v) {
#pragma unroll
    for (int off = 32; off > 0; off >>= 1) v += __shfl_xor(v, off, 64);
    return v;
}

// ---------------- setup: xb convert + deg histogram + graph boundaries -----
__global__ void setup_kernel(const float* __restrict__ x, ushort* __restrict__ xb,
                             const int* __restrict__ dst, int* __restrict__ deg,
                             const int* __restrict__ batch, int* __restrict__ gstart,
                             int total, int N, int E, int G) {
    int idx = blockIdx.x * blockDim.x + threadIdx.x;
    if (idx >= total) return;
    xb[idx] = f2bf(x[idx]);
    if (idx < E) atomicAdd(&deg[dst[idx]], 1);
    if (idx < N) {
        int bb = batch[idx];
        if (idx == 0)
            for (int g = 0; g <= bb; g++) gstart[g] = 0;
        else {
            int pb = batch[idx - 1];
            for (int g = pb + 1; g <= bb; g++) gstart[g] = idx;
        }
        if (idx == N - 1)
            for (int g = bb + 1; g <= G; g++) gstart[g] = N;
    }
}

// single-workgroup exclusive scan of deg -> offs, cursor
__global__ __launch_bounds__(1024) void scan_kernel(const int* __restrict__ deg,
                                                    int* __restrict__ offs,
                                                    int* __restrict__ cursor, int N) {
    __shared__ int part[1024];
    int tid = threadIdx.x;
    int CH = (N + 1023) / 1024;
    int base = tid * CH;
    int s = 0;
    for (int i = 0; i < CH; i++) {
        int idx = base + i;
        if (idx < N) s += deg[idx];
    }
    part[tid] = s;
    __syncthreads();
    for (int off = 1; off < 1024; off <<= 1) {
        int v = (tid >= off) ? part[tid - off] : 0;
        __syncthreads();
        part[tid] += v;
        __syncthreads();
    }
    int run = (tid == 0) ? 0 : part[tid - 1];
    for (int i = 0; i < CH; i++) {
        int idx = base + i;
        if (idx < N) {
            offs[idx] = run;
            cursor[idx] = run;
            run += deg[idx];
        }
    }
    if (tid == 1023) offs[N] = part[1023];
}

__global__ void scatter_kernel(const int* __restrict__ src, const int* __restrict__ dst,
                               int* __restrict__ cursor, int* __restrict__ esrc, int E) {
    int e = blockIdx.x * blockDim.x + threadIdx.x;
    if (e < E) {
        int d = dst[e];
        int pos = atomicAdd(&cursor[d], 1);
        esrc[pos] = src[e];
    }
}

// ---------------- weight prep: fp32 [R][C] -> bf16 [C][R], all matrices ----
__global__ __launch_bounds__(256) void prep_kernel(const float* __restrict__ W1,
                                                   const float* __restrict__ W2,
                                                   const float* __restrict__ encW,
                                                   ushort* __restrict__ W1t,
                                                   ushort* __restrict__ W2t,
                                                   ushort* __restrict__ encWt, int L) {
    __shared__ float tile[32][33];
    int z = blockIdx.z;
    const float* in;
    ushort* out;
    int R, C;
    if (z < L) {
        in = W1 + (size_t)z * 32768; out = W1t + (size_t)z * 32768; R = 128; C = 256;
    } else if (z < 2 * L) {
        int i = z - L;
        in = W2 + (size_t)i * 32768; out = W2t + (size_t)i * 32768; R = 256; C = 128;
    } else {
        in = encW; out = encWt; R = 128; C = 128;
    }
    int r0 = blockIdx.y * 32, c0 = blockIdx.x * 32;
    if (r0 >= R || c0 >= C) return;
    int tx = threadIdx.x & 31, ty = threadIdx.x >> 5;
    for (int i = ty; i < 32; i += 8) tile[i][tx] = in[(size_t)(r0 + i) * C + c0 + tx];
    __syncthreads();
    for (int i = ty; i < 32; i += 8)
        out[(size_t)(c0 + i) * R + r0 + tx] = f2bf(tile[tx][i]);
}

// ---- aggregation v13: 2 nodes/wave; wave-preloaded indices + half-wave
// uint2 gathers (8 edges in flight per node per iteration). Max-free softmax
// (z = (relu+eps)*t bounded -> exp safe), fully associative accumulation. ----
__device__ __forceinline__ void agg_stage_v13(const ushort* __restrict__ rin,
                                              const int* __restrict__ offs,
                                              const int* __restrict__ esrc,
                                              const float* __restrict__ rnbuf,
                                              float tv, float sv, int row0,
                                              int w, int l, uint (*AsU)[68]) {
    const uint2* rin2 = (const uint2*)rin;
    int nd0 = row0 + 2 * w;
    int half = l >> 5, li = l & 31;
    int a0 = offs[nd0], a1 = offs[nd0 + 1], a2 = offs[nd0 + 2];
    int eb[2] = {a0, a1};
    int dg[2] = {a1 - a0, a2 - a1};

    float s[2][4] = {}, W[2][4] = {};
    int mxdeg = max(dg[0], dg[1]);

#pragma unroll 1
    for (int base = 0; base < mxdeg; base += 64) {
        int rem0 = min(dg[0] - base, 64);
        int rem1 = min(dg[1] - base, 64);
        int idx0 = (rem0 > 0 && l < rem0) ? esrc[eb[0] + base + l] : 0;
        int idx1 = (rem1 > 0 && l < rem1) ? esrc[eb[1] + base + l] : 0;
        int it = (max(rem0, rem1) + 7) >> 3;
#pragma unroll 1
        for (int i = 0; i < it; i++) {
            int j0 = i * 8 + half;
            uint2 rv[2][4];
            bool vl[2][4];
#pragma unroll
            for (int c = 0; c < 4; c++) {
                int j = j0 + 2 * c;
                vl[0][c] = j < rem0;
                vl[1][c] = j < rem1;
                int sn0 = __shfl(idx0, j, 64);
                int sn1 = __shfl(idx1, j, 64);
                if (vl[0][c]) rv[0][c] = rin2[(size_t)sn0 * 32 + li];
                if (vl[1][c]) rv[1][c] = rin2[(size_t)sn1 * 32 + li];
            }
#pragma unroll
            for (int k = 0; k < 2; k++)
#pragma unroll
                for (int c = 0; c < 4; c++) {
                    if (vl[k][c]) {
                        float f0 = bf2f((ushort)(rv[k][c].x & 0xffff));
                        float f1 = bf2f((ushort)(rv[k][c].x >> 16));
                        float f2 = bf2f((ushort)(rv[k][c].y & 0xffff));
                        float f3 = bf2f((ushort)(rv[k][c].y >> 16));
                        float g0 = fmaxf(f0, 0.f) + 1e-7f;
                        float g1 = fmaxf(f1, 0.f) + 1e-7f;
                        float g2 = fmaxf(f2, 0.f) + 1e-7f;
                        float g3 = fmaxf(f3, 0.f) + 1e-7f;
                        float p0 = __expf(g0 * tv);
                        float p1 = __expf(g1 * tv);
                        float p2 = __expf(g2 * tv);
                        float p3 = __expf(g3 * tv);
                        s[k][0] += p0; W[k][0] += g0 * p0;
                        s[k][1] += p1; W[k][1] += g1 * p1;
                        s[k][2] += p2; W[k][2] += g2 * p2;
                        s[k][3] += p3; W[k][3] += g3 * p3;
                    }
                }
        }
    }

    // merge halves (associative sums), then per-node epilogue
#pragma unroll
    for (int k = 0; k < 2; k++) {
#pragma unroll
        for (int f = 0; f < 4; f++) {
            s[k][f] += __shfl_xor(s[k][f], 32, 64);
            W[k][f] += __shfl_xor(W[k][f], 32, 64);
        }
        float agg[4], nsq = 0.f;
#pragma unroll
        for (int f = 0; f < 4; f++) {
            agg[f] = W[k][f] / (s[k][f] + 1e-16f);
            nsq += agg[f] * agg[f];
        }
        // sum over the 32 lanes of each half (halves hold identical values)
#pragma unroll
        for (int off = 1; off < 32; off <<= 1) nsq += __shfl_xor(nsq, off, 64);
        int nd = nd0 + k;
        float fac = rnbuf[nd] * sv / fmaxf(sqrtf(nsq), 1e-12f);
        uint2 ru = rin2[(size_t)nd * 32 + li];
        if (half == 0) {
            uint2 o;
            o.x = f2bf2(bf2f((ushort)(ru.x & 0xffff)) + agg[0] * fac,
                        bf2f((ushort)(ru.x >> 16)) + agg[1] * fac);
            o.y = f2bf2(bf2f((ushort)(ru.y & 0xffff)) + agg[2] * fac,
                        bf2f((ushort)(ru.y >> 16)) + agg[3] * fac);
            *(uint2*)&AsU[2 * w + k][2 * li] = o;
        }
    }
}

// ---- gemm1 (8 waves): z1 = relu(LN256(A(16x128) @ W1^T + b1)) into LDS ----
__device__ __forceinline__ void gemm1_stage8(const ushort (*As)[136],
                                             const ushort* __restrict__ Bt,
                                             const float* __restrict__ bias,
                                             const float* __restrict__ mg,
                                             const float* __restrict__ mb,
                                             ushort (*z1s)[264],
                                             int w, int q, int ln,
                                             float (*pS)[16], float (*pQ)[16]) {
    f32x4 acc[2];
    acc[0] = (f32x4){0.f, 0.f, 0.f, 0.f};
    acc[1] = (f32x4){0.f, 0.f, 0.f, 0.f};
#pragma unroll
    for (int ks = 0; ks < 128; ks += 32) {
        bf16x8 a = *(const bf16x8*)&As[ln][ks + q * 8];
#pragma unroll
        for (int ct = 0; ct < 2; ct++) {
            bf16x8 bv = *(const bf16x8*)(Bt + (size_t)(w * 32 + ct * 16 + ln) * 128 + ks + q * 8);
            acc[ct] = __builtin_amdgcn_mfma_f32_16x16x32_bf16(a, bv, acc[ct], 0, 0, 0);
        }
    }
    float s1[4] = {0, 0, 0, 0}, s2[4] = {0, 0, 0, 0};
#pragma unroll
    for (int ct = 0; ct < 2; ct++)
#pragma unroll
        for (int r = 0; r < 4; r++) {
            float v = acc[ct][r] + bias[w * 32 + ct * 16 + ln];
            acc[ct][r] = v;
            s1[r] += v;
            s2[r] += v * v;
        }
#pragma unroll
    for (int off = 1; off < 16; off <<= 1)
#pragma unroll
        for (int r = 0; r < 4; r++) {
            s1[r] += __shfl_xor(s1[r], off, 64);
            s2[r] += __shfl_xor(s2[r], off, 64);
        }
    if (ln == 0)
#pragma unroll
        for (int r = 0; r < 4; r++) {
            pS[w][q * 4 + r] = s1[r];
            pQ[w][q * 4 + r] = s2[r];
        }
    __syncthreads();
#pragma unroll
    for (int r = 0; r < 4; r++) {
        int row = q * 4 + r;
        float S = 0.f, Q = 0.f;
#pragma unroll
        for (int ww = 0; ww < 8; ww++) {
            S += pS[ww][row];
            Q += pQ[ww][row];
        }
        float mu = S * (1.f / 256.f);
        float var = Q * (1.f / 256.f) - mu * mu;
        float rs = rsqrtf(var + 1e-5f);
#pragma unroll
        for (int ct = 0; ct < 2; ct++) {
            int col = w * 32 + ct * 16 + ln;
            float y = (acc[ct][r] - mu) * rs * mg[col] + mb[col];
            z1s[row][col] = f2bf(fmaxf(y, 0.f));
        }
    }
    __syncthreads();
}

// ---- out gemm (8 waves): v = A(16xKD)@B^T + bias (+h); h=v; LN128+lrelu ---
template <int KD, bool RESID>
__device__ __forceinline__ void out_stage8(const ushort* __restrict__ Abase, int astr,
                                           const ushort* __restrict__ Bt,
                                           const float* __restrict__ bias,
                                           const float* __restrict__ lg,
                                           const float* __restrict__ lb,
                                           float* __restrict__ hbuf,
                                           ushort* __restrict__ rout,
                                           float* __restrict__ rnbuf,
                                           int row0, int w, int q, int ln,
                                           float (*pS)[16], float (*pQ)[16]) {
    f32x4 acc = (f32x4){0.f, 0.f, 0.f, 0.f};
    int col = w * 16 + ln;
#pragma unroll
    for (int ks = 0; ks < KD; ks += 32) {
        bf16x8 a = *(const bf16x8*)(Abase + ln * astr + ks + q * 8);
        bf16x8 bv = *(const bf16x8*)(Bt + (size_t)col * KD + ks + q * 8);
        acc = __builtin_amdgcn_mfma_f32_16x16x32_bf16(a, bv, acc, 0, 0, 0);
    }
    float s1[4], s2[4];
#pragma unroll
    for (int r = 0; r < 4; r++) {
        int row = q * 4 + r;
        float v = acc[r] + bias[col];
        if (RESID) v += hbuf[(size_t)(row0 + row) * 128 + col];
        hbuf[(size_t)(row0 + row) * 128 + col] = v;
        acc[r] = v;
        s1[r] = v;
        s2[r] = v * v;
    }
#pragma unroll
    for (int off = 1; off < 16; off <<= 1)
#pragma unroll
        for (int r = 0; r < 4; r++) {
            s1[r] += __shfl_xor(s1[r], off, 64);
            s2[r] += __shfl_xor(s2[r], off, 64);
        }
    if (ln == 0)
#pragma unroll
        for (int r = 0; r < 4; r++) {
            pS[w][q * 4 + r] = s1[r];
            pQ[w][q * 4 + r] = s2[r];
        }
    __syncthreads();
    float yv[4];
    float t2[4];
#pragma unroll
    for (int r = 0; r < 4; r++) {
        int row = q * 4 + r;
        float S = 0.f, Q = 0.f;
#pragma unroll
        for (int ww = 0; ww < 8; ww++) {
            S += pS[ww][row];
            Q += pQ[ww][row];
        }
        float mu = S * (1.f / 128.f);
        float var = Q * (1.f / 128.f) - mu * mu;
        float rs = rsqrtf(var + 1e-5f);
        float y = (acc[r] - mu) * rs * lg[col] + lb[col];
        y = y > 0.f ? y : 0.01f * y;
        yv[r] = y;
        t2[r] = y * y;
    }
#pragma unroll
    for (int off = 1; off < 16; off <<= 1)
#pragma unroll
        for (int r = 0; r < 4; r++) t2[r] += __shfl_xor(t2[r], off, 64);
    __syncthreads();
    if (ln == 0)
#pragma unroll
        for (int r = 0; r < 4; r++) pS[w][q * 4 + r] = t2[r];
    __syncthreads();
#pragma unroll
    for (int r = 0; r < 4; r++) {
        int row = q * 4 + r;
        float T = 0.f;
#pragma unroll
        for (int ww = 0; ww < 8; ww++) T += pS[ww][row];
        if (w == 0 && ln == 0) rnbuf[row0 + row] = sqrtf(T);
        rout[(size_t)(row0 + row) * 128 + col] = f2bf(yv[r]);
    }
}

// ---------------- encoder: h = xb @ encW^T + b; LN0 + lrelu ----------------
__global__ __launch_bounds__(BT) void enc_kernel(const ushort* __restrict__ xb,
                                                 const ushort* __restrict__ encWt,
                                                 const float* __restrict__ encB,
                                                 const float* __restrict__ lg,
                                                 const float* __restrict__ lb,
                                                 float* __restrict__ h,
                                                 ushort* __restrict__ r,
                                                 float* __restrict__ rn, int N) {
    __shared__ __align__(16) ushort As[16][136];
    __shared__ float pS[8][16], pQ[8][16];
    uint(*AsU)[68] = (uint(*)[68])As;
    int tid = threadIdx.x, w = tid >> 6, l = tid & 63;
    int q = l >> 4, ln = l & 15;
    int row0 = blockIdx.x * 16;
    for (int idx = tid; idx < 16 * 64; idx += BT) {
        int row = idx >> 6, cl = idx & 63;
        AsU[row][cl] = ((const uint*)xb)[(size_t)(row0 + row) * 64 + cl];
    }
    __syncthreads();
    out_stage8<128, false>(&As[0][0], 136, encWt, encB, lg, lb, h, r, rn,
                           row0, w, q, ln, pS, pQ);
}

// ---------------- fused layer: 16-row tile, agg + gemm1 + gemm2 ------------
__global__ __launch_bounds__(BT) void layer_kernel(const ushort* __restrict__ rin,
                                                   ushort* __restrict__ rout,
                                                   const int* __restrict__ offs,
                                                   const int* __restrict__ esrc,
                                                   float* __restrict__ rn,
                                                   float* __restrict__ h,
                                                   const ushort* __restrict__ W1t,
                                                   const ushort* __restrict__ W2t,
                                                   const float* __restrict__ b1,
                                                   const float* __restrict__ mg,
                                                   const float* __restrict__ mb,
                                                   const float* __restrict__ b2,
                                                   const float* __restrict__ ng,
                                                   const float* __restrict__ nb,
                                                   const float* __restrict__ tptr,
                                                   const float* __restrict__ scptr,
                                                   int N) {
    __shared__ __align__(16) ushort As[16][136];
    __shared__ __align__(16) ushort z1s[16][264];
    __shared__ float pS[8][16], pQ[8][16];
    uint(*AsU)[68] = (uint(*)[68])As;
    int tid = threadIdx.x, w = tid >> 6, l = tid & 63;
    int q = l >> 4, ln = l & 15;
    int row0 = blockIdx.x * 16;
    float tv = *tptr, sv = *scptr;
    agg_stage_v13(rin, offs, esrc, rn, tv, sv, row0, w, l, AsU);
    __syncthreads();
    gemm1_stage8(As, W1t, b1, mg, mb, z1s, w, q, ln, pS, pQ);
    out_stage8<256, true>(&z1s[0][0], 264, W2t, b2, ng, nb, h, rout, rn,
                          row0, w, q, ln, pS, pQ);
}

// ---------------- pool: one block per graph, 4 waves over rows -------------
__global__ __launch_bounds__(256) void pool_kernel(const ushort* __restrict__ rf,
                                                   const int* __restrict__ gstart,
                                                   float* __restrict__ out) {
    __shared__ float pb0[4][64], pb1[4][64];
    int g = blockIdx.x;
    int w = threadIdx.x >> 6, l = threadIdx.x & 63;
    int s = gstart[g], e = gstart[g + 1];
    float a0 = 0.f, a1 = 0.f;
    for (int n = s + w; n < e; n += 4) {
        uint rv = ((const uint*)rf)[(size_t)n * 64 + l];
        a0 += bf2f((ushort)(rv & 0xffff));
        a1 += bf2f((ushort)(rv >> 16));
    }
    pb0[w][l] = a0;
    pb1[w][l] = a1;
    __syncthreads();
    if (threadIdx.x < 64) {
        float t0 = pb0[0][l] + pb0[1][l] + pb0[2][l] + pb0[3][l];
        float t1 = pb1[0][l] + pb1[1][l] + pb1[2][l] + pb1[3][l];
        float inv = 1.f / fmaxf((float)(e - s), 1.f);
        out[g * 128 + 2 * l] = t0 * inv;
        out[g * 128 + 2 * l + 1] = t1 * inv;
    }
}

// ---------------------------------------------------------------------------
extern "C" void kernel_launch(void* const* d_in, const int* in_sizes, int n_in,
                              void* d_out, int out_size, void* d_ws, size_t ws_size,
                              hipStream_t stream) {
    const float* x     = (const float*)d_in[0];
    const int*   ei    = (const int*)d_in[1];
    const int*   batch = (const int*)d_in[2];
    const float* encW  = (const float*)d_in[3];
    const float* encB  = (const float*)d_in[4];
    const float* ln_g  = (const float*)d_in[5];
    const float* ln_b  = (const float*)d_in[6];
    const float* tArr  = (const float*)d_in[7];
    const float* scArr = (const float*)d_in[8];
    const float* W1    = (const float*)d_in[9];
    const float* b1    = (const float*)d_in[10];
    const float* mg    = (const float*)d_in[11];
    const float* mb    = (const float*)d_in[12];
    const float* W2    = (const float*)d_in[13];
    const float* b2    = (const float*)d_in[14];
    const float* fn_g  = (const float*)d_in[15];
    const float* fn_b  = (const float*)d_in[16];
    float* out = (float*)d_out;

    const int N = in_sizes[0] / 128;  // 10000
    const int E = in_sizes[1] / 2;    // 160000
    const int L = in_sizes[7];        // 14
    const int G = 64;

    const int* src = ei;
    const int* dst = ei + E;

    char* p = (char*)d_ws;
    auto alloc = [&](size_t bytes) -> void* {
        void* qp = (void*)p;
        p += (bytes + 255) & ~(size_t)255;
        return qp;
    };
    int*    deg    = (int*)alloc((size_t)N * 4);
    int*    offs   = (int*)alloc((size_t)(N + 1) * 4);
    int*    cursor = (int*)alloc((size_t)N * 4);
    int*    esrc   = (int*)alloc((size_t)E * 4);
    int*    gstart = (int*)alloc((size_t)(G + 1) * 4);
    float*  h      = (float*)alloc((size_t)N * 128 * 4);
    ushort* r0     = (ushort*)alloc((size_t)N * 128 * 2);
    ushort* r1     = (ushort*)alloc((size_t)N * 128 * 2);
    float*  rn     = (float*)alloc((size_t)N * 4);
    ushort* xb     = (ushort*)alloc((size_t)N * 128 * 2);
    ushort* W1t    = (ushort*)alloc((size_t)L * 32768 * 2);
    ushort* W2t    = (ushort*)alloc((size_t)L * 32768 * 2);
    ushort* encWt  = (ushort*)alloc((size_t)16384 * 2);

    (void)hipMemsetAsync(deg, 0, (size_t)N * 4, stream);

    setup_kernel<<<(N * 128 + 255) / 256, 256, 0, stream>>>(x, xb, dst, deg, batch,
                                                            gstart, N * 128, N, E, G);
    scan_kernel<<<1, 1024, 0, stream>>>(deg, offs, cursor, N);
    scatter_kernel<<<(E + 255) / 256, 256, 0, stream>>>(src, dst, cursor, esrc, E);
    prep_kernel<<<dim3(8, 8, 2 * L + 1), 256, 0, stream>>>(W1, W2, encW, W1t, W2t,
                                                           encWt, L);

    const int TILES = N / 16;  // 625

    enc_kernel<<<TILES, BT, 0, stream>>>(xb, encWt, encB, ln_g, ln_b, h, r0, rn, N);

    for (int i = 0; i < L; i++) {
        const ushort* rin = (i & 1) ? r1 : r0;
        ushort* rout = (i & 1) ? r0 : r1;
        const float* ng = (i < L - 1) ? (ln_g + (size_t)(i + 1) * 128) : fn_g;
        const float* nb = (i < L - 1) ? (ln_b + (size_t)(i + 1) * 128) : fn_b;
        layer_kernel<<<TILES, BT, 0, stream>>>(rin, rout, offs, esrc, rn, h,
                                               W1t + ((size_t)i << 15),
                                               W2t + ((size_t)i << 15),
                                               b1 + (size_t)i * 256,
                                               mg + (size_t)i * 256,
                                               mb + (size_t)i * 256,
                                               b2 + (size_t)i * 128,
                                               ng, nb, tArr + i, scArr + i, N);
    }

    // last layer i=L-1 wrote rout = ((L-1)&1) ? r0 : r1
    const ushort* rf = ((L - 1) & 1) ? r0 : r1;
    pool_kernel<<<G, 256, 0, stream>>>(rf, gstart, out);
}